// Round 1
// baseline (656.365 us; speedup 1.0000x reference)
//
#include <hip/hip_runtime.h>
#include <stdint.h>

// Problem sizes (fixed by the reference)
#define NQn 131072
#define NCn 65536
#define En  1048576
// D = 128, HID = 256

typedef __bf16 bf16;
typedef __bf16 bf16x2 __attribute__((ext_vector_type(2)));
typedef __bf16 bf16x4 __attribute__((ext_vector_type(4)));
typedef __bf16 bf16x8 __attribute__((ext_vector_type(8)));
typedef float  f32x4  __attribute__((ext_vector_type(4)));

// ---------------------------------------------------------------------------
// Weight transpose + bf16 cast: Wt[m*K+k] = bf16(W[k*M+m])
// blockIdx.y selects which weight (8 total).
// ---------------------------------------------------------------------------
__global__ void wtrans_all(
    const float* __restrict__ w0, bf16* __restrict__ t0,
    const float* __restrict__ w1, bf16* __restrict__ t1,
    const float* __restrict__ w2, bf16* __restrict__ t2,
    const float* __restrict__ w3, bf16* __restrict__ t3,
    const float* __restrict__ w4, bf16* __restrict__ t4,
    const float* __restrict__ w5, bf16* __restrict__ t5,
    const float* __restrict__ w6, bf16* __restrict__ t6,
    const float* __restrict__ w7, bf16* __restrict__ t7) {
  const float* W; bf16* T; int K, M;
  switch (blockIdx.y) {
    case 0: W = w0; T = t0; K = 128; M = 128; break;  // Wres_Q
    case 1: W = w1; T = t1; K = 128; M = 128; break;  // Wres_C
    case 2: W = w2; T = t2; K = 128; M = 128; break;  // Wrel_QC
    case 3: W = w3; T = t3; K = 128; M = 128; break;  // Wrel_CQ
    case 4: W = w4; T = t4; K = 256; M = 256; break;  // W1_Q
    case 5: W = w5; T = t5; K = 256; M = 256; break;  // W1_C
    case 6: W = w6; T = t6; K = 256; M = 128; break;  // W2_Q
    default: W = w7; T = t7; K = 256; M = 128; break; // W2_C
  }
  int t = blockIdx.x * 256 + threadIdx.x;
  if (t >= K * M) return;
  int m = t % M, k = t / M;
  T[m * K + k] = (bf16)W[k * M + m];
}

// ---------------------------------------------------------------------------
// Row LayerNorm -> bf16. One wave (64 lanes) per row, 2 elems/lane.
// ---------------------------------------------------------------------------
__global__ __launch_bounds__(256) void ln_kernel(
    const float* __restrict__ H, const float* __restrict__ g,
    const float* __restrict__ b, bf16* __restrict__ out, int nrows) {
  int row = blockIdx.x * 4 + (threadIdx.x >> 6);
  if (row >= nrows) return;
  int lane = threadIdx.x & 63;
  const float* rp = H + (size_t)row * 128;
  float2 v = *(const float2*)(rp + lane * 2);
  float s = v.x + v.y;
  #pragma unroll
  for (int o = 32; o; o >>= 1) s += __shfl_xor(s, o, 64);
  float mean = s * (1.0f / 128.0f);
  float dx = v.x - mean, dy = v.y - mean;
  float q = dx * dx + dy * dy;
  #pragma unroll
  for (int o = 32; o; o >>= 1) q += __shfl_xor(q, o, 64);
  float rs = rsqrtf(q * (1.0f / 128.0f) + 1e-5f);
  float2 gg = *(const float2*)(g + lane * 2);
  float2 bb = *(const float2*)(b + lane * 2);
  bf16x2 r;
  r[0] = (bf16)(dx * rs * gg.x + bb.x);
  r[1] = (bf16)(dy * rs * gg.y + bb.y);
  *(bf16x2*)(out + (size_t)row * 128 + lane * 2) = r;
}

// ---------------------------------------------------------------------------
// Generic 128x128-tile bf16 MFMA GEMM: C[N x (NK*128)] = A[N x (NK*128)] @ B
// Bt is the pre-transposed weight, M x K bf16 (row-major, K contiguous).
// A chunk kc comes from (kc==0 ? A0 : A1) at element offset kc*kOff.
// Epilogues: 0 store bf16; 1 row-scale(inv_sqrt deg_src) store bf16;
//            2 +bias, exact GELU, store bf16; 3 +bias +resid, store f32.
// LDS XOR swizzle (byte ^= (row&7)<<4) applied on both write and read.
// ---------------------------------------------------------------------------
#define ASRC_BF16 0
#define ASRC_F32  1
#define EPI_BF16  0
#define EPI_RSCL  1
#define EPI_GELU  2
#define EPI_RES   3

template <int ASRC, int EPI, int NK>
__global__ __launch_bounds__(256, 2) void gemm_kernel(
    const void* __restrict__ A0, const void* __restrict__ A1,
    const bf16* __restrict__ Bt, const float* __restrict__ bias,
    const float* __restrict__ rowscale, const bf16* __restrict__ resid,
    bf16* __restrict__ outB, float* __restrict__ outF,
    int ldA, int kOff, int ldOut) {
  __shared__ __align__(16) unsigned char lds[65536];
  const int tid = threadIdx.x;
  const int row0 = blockIdx.x * 128;
  const int col0 = blockIdx.y * 128;
  const int wid = tid >> 6, lane = tid & 63;
  const int wrow = (wid >> 1) * 64, wcol = (wid & 1) * 64;

  f32x4 acc[4][4] = {};

  #pragma unroll
  for (int kc = 0; kc < NK; ++kc) {
    if (kc) __syncthreads();
    const void* ap = (kc == 0) ? A0 : A1;
    const int kofs = kc * kOff;
    if (ASRC == ASRC_F32) {
      const float* Af = (const float*)ap;
      #pragma unroll
      for (int it = 0; it < 16; ++it) {
        int lin = it * 256 + tid;       // float4 group id, 4096 total
        int r = lin >> 5;               // 32 groups per 128-col row
        int c = (lin & 31) * 4;
        float4 v = *(const float4*)(Af + (size_t)(row0 + r) * ldA + kofs + c);
        bf16x4 w;
        w[0] = (bf16)v.x; w[1] = (bf16)v.y; w[2] = (bf16)v.z; w[3] = (bf16)v.w;
        *(bf16x4*)(lds + r * 256 + ((c * 2) ^ ((r & 7) << 4))) = w;
      }
    } else {
      const bf16* Ab = (const bf16*)ap;
      #pragma unroll
      for (int it = 0; it < 8; ++it) {
        int lin = it * 256 + tid;       // 16B chunk id, 2048 total
        int r = lin >> 4;               // 16 chunks per 256B row
        int cb = (lin & 15) * 16;       // byte offset in row
        bf16x8 v = *(const bf16x8*)((const char*)Ab +
                    ((size_t)(row0 + r) * ldA + kofs) * 2 + cb);
        *(bf16x8*)(lds + r * 256 + (cb ^ ((r & 7) << 4))) = v;
      }
    }
    // stage Bt tile (always bf16, ld = NK*128)
    #pragma unroll
    for (int it = 0; it < 8; ++it) {
      int lin = it * 256 + tid;
      int r = lin >> 4;
      int cb = (lin & 15) * 16;
      bf16x8 v = *(const bf16x8*)((const char*)Bt +
                  ((size_t)(col0 + r) * (NK * 128) + kc * 128) * 2 + cb);
      *(bf16x8*)(lds + 32768 + r * 256 + (cb ^ ((r & 7) << 4))) = v;
    }
    __syncthreads();
    #pragma unroll
    for (int kk = 0; kk < 4; ++kk) {
      bf16x8 af[4], bfv[4];
      const int kb = kk * 64 + (lane >> 4) * 16;
      #pragma unroll
      for (int fr = 0; fr < 4; ++fr) {
        int ar = wrow + fr * 16 + (lane & 15);
        af[fr] = *(const bf16x8*)(lds + ar * 256 + (kb ^ ((ar & 7) << 4)));
      }
      #pragma unroll
      for (int fc = 0; fc < 4; ++fc) {
        int br = wcol + fc * 16 + (lane & 15);
        bfv[fc] = *(const bf16x8*)(lds + 32768 + br * 256 + (kb ^ ((br & 7) << 4)));
      }
      #pragma unroll
      for (int fr = 0; fr < 4; ++fr)
        #pragma unroll
        for (int fc = 0; fc < 4; ++fc)
          acc[fr][fc] = __builtin_amdgcn_mfma_f32_16x16x32_bf16(
              af[fr], bfv[fc], acc[fr][fc], 0, 0, 0);
    }
  }

  const int rbase = row0 + wrow + (lane >> 4) * 4;
  const int cbase = col0 + wcol + (lane & 15);
  #pragma unroll
  for (int fr = 0; fr < 4; ++fr) {
    float rs[4];
    if (EPI == EPI_RSCL) {
      #pragma unroll
      for (int r = 0; r < 4; ++r) {
        float dv = rowscale[rbase + fr * 16 + r];
        rs[r] = dv > 0.f ? rsqrtf(dv) : 0.f;
      }
    }
    #pragma unroll
    for (int fc = 0; fc < 4; ++fc) {
      const int col = cbase + fc * 16;
      float bv = (EPI == EPI_GELU || EPI == EPI_RES) ? bias[col] : 0.f;
      #pragma unroll
      for (int r = 0; r < 4; ++r) {
        const int row = rbase + fr * 16 + r;
        float x = acc[fr][fc][r];
        if (EPI == EPI_BF16) {
          outB[(size_t)row * ldOut + col] = (bf16)x;
        } else if (EPI == EPI_RSCL) {
          outB[(size_t)row * ldOut + col] = (bf16)(x * rs[r]);
        } else if (EPI == EPI_GELU) {
          x += bv;
          x = 0.5f * x * (1.f + erff(x * 0.70710678118f));
          outB[(size_t)row * ldOut + col] = (bf16)x;
        } else {
          x += bv + (float)resid[(size_t)row * 128 + col];
          outF[(size_t)row * 128 + col] = x;
        }
      }
    }
  }
}

// ---------------------------------------------------------------------------
// CSR build: histogram -> 2-level exclusive scan -> fill
// ---------------------------------------------------------------------------
__global__ void hist_kernel(const int* __restrict__ dst, int* __restrict__ cur) {
  int e = blockIdx.x * 256 + threadIdx.x;
  if (e < En) atomicAdd(&cur[dst[e]], 1);
}

__global__ __launch_bounds__(1024) void scan_local(
    const int* __restrict__ cnt, int* __restrict__ offs, int* __restrict__ bsum) {
  __shared__ int s[1024];
  int i = blockIdx.x * 1024 + threadIdx.x;
  int v = cnt[i];
  s[threadIdx.x] = v;
  __syncthreads();
  for (int o = 1; o < 1024; o <<= 1) {
    int x = (threadIdx.x >= o) ? s[threadIdx.x - o] : 0;
    __syncthreads();
    s[threadIdx.x] += x;
    __syncthreads();
  }
  offs[i] = s[threadIdx.x] - v;
  if (threadIdx.x == 1023) bsum[blockIdx.x] = s[1023];
}

__global__ void scan_bsum(int* bsum, int nb) {
  if (threadIdx.x == 0 && blockIdx.x == 0) {
    int run = 0;
    for (int j = 0; j < nb; ++j) { int t = bsum[j]; bsum[j] = run; run += t; }
  }
}

__global__ void scan_add(int* __restrict__ offs, int* __restrict__ cur,
                         const int* __restrict__ bsum) {
  int i = blockIdx.x * 256 + threadIdx.x;
  int v = offs[i] + bsum[i >> 10];
  offs[i] = v;
  cur[i] = v;
}

__global__ void fill_kernel(const int* __restrict__ esrc, const int* __restrict__ edst,
                            int* __restrict__ cur, int* __restrict__ csr) {
  int e = blockIdx.x * 256 + threadIdx.x;
  if (e < En) {
    int p = atomicAdd(&cur[edst[e]], 1);
    csr[p] = esrc[e];
  }
}

// ---------------------------------------------------------------------------
// Gather: one wave per dst row; msg[d] = (sum_src Xn[src]) * invsqrt(deg_dst)*gate
// ---------------------------------------------------------------------------
__global__ __launch_bounds__(256) void gather_kernel(
    const bf16* __restrict__ Xn, const int* __restrict__ csr,
    const int* __restrict__ offs, const float* __restrict__ degdst,
    const float* __restrict__ gate, bf16* __restrict__ msg, int ndst) {
  int d = blockIdx.x * 4 + (threadIdx.x >> 6);
  if (d >= ndst) return;
  int lane = threadIdx.x & 63;
  float dv = degdst[d];
  int cnt = (int)(dv + 0.5f);
  int start = offs[d];
  float ax = 0.f, ay = 0.f;
  int i = 0;
  for (; i + 2 <= cnt; i += 2) {
    int s0 = csr[start + i], s1 = csr[start + i + 1];
    bf16x2 v0 = *(const bf16x2*)(Xn + (size_t)s0 * 128 + lane * 2);
    bf16x2 v1 = *(const bf16x2*)(Xn + (size_t)s1 * 128 + lane * 2);
    ax += (float)v0[0] + (float)v1[0];
    ay += (float)v0[1] + (float)v1[1];
  }
  if (i < cnt) {
    int s0 = csr[start + i];
    bf16x2 v0 = *(const bf16x2*)(Xn + (size_t)s0 * 128 + lane * 2);
    ax += (float)v0[0];
    ay += (float)v0[1];
  }
  float sc = (dv > 0.f ? rsqrtf(dv) : 0.f) * gate[0];
  bf16x2 r;
  r[0] = (bf16)(ax * sc);
  r[1] = (bf16)(ay * sc);
  *(bf16x2*)(msg + (size_t)d * 128 + lane * 2) = r;
}

// ---------------------------------------------------------------------------
extern "C" void kernel_launch(void* const* d_in, const int* in_sizes, int n_in,
                              void* d_out, int out_size, void* d_ws, size_t ws_size,
                              hipStream_t stream) {
  const float* H_Q        = (const float*)d_in[0];
  const float* H_C        = (const float*)d_in[1];
  const int*   eQC_src    = (const int*)d_in[2];
  const int*   eQC_dst    = (const int*)d_in[3];
  const int*   eCQ_src    = (const int*)d_in[4];
  const int*   eCQ_dst    = (const int*)d_in[5];
  const float* deg_QC_src = (const float*)d_in[6];
  const float* deg_QC_dst = (const float*)d_in[7];
  const float* deg_CQ_src = (const float*)d_in[8];
  const float* deg_CQ_dst = (const float*)d_in[9];
  const float* ln_g_Q     = (const float*)d_in[10];
  const float* ln_b_Q     = (const float*)d_in[11];
  const float* Wres_Q     = (const float*)d_in[12];
  const float* ln_g_C     = (const float*)d_in[13];
  const float* ln_b_C     = (const float*)d_in[14];
  const float* Wres_C     = (const float*)d_in[15];
  const float* Wrel_QC    = (const float*)d_in[16];
  const float* Wrel_CQ    = (const float*)d_in[17];
  const float* gate_QC    = (const float*)d_in[18];
  const float* gate_CQ    = (const float*)d_in[19];
  const float* W1_Q       = (const float*)d_in[20];
  const float* b1_Q       = (const float*)d_in[21];
  const float* W2_Q       = (const float*)d_in[22];
  const float* b2_Q       = (const float*)d_in[23];
  const float* W1_C       = (const float*)d_in[24];
  const float* b1_C       = (const float*)d_in[25];
  const float* W2_C       = (const float*)d_in[26];
  const float* b2_C       = (const float*)d_in[27];

  char* ws = (char*)d_ws;
  size_t o = 0;
  auto alloc = [&](size_t bytes) -> char* {
    char* p = ws + o;
    o += (bytes + 255) & ~(size_t)255;
    return p;
  };
  // R0 overlay: {lnbQ, lnbC, xnbQ, xnbC} (phase 1-2) == {hQ, hC} (phase 3)
  char* r0 = alloc(100663296);
  bf16* lnbQ = (bf16*)r0;                     // 33554432 B
  bf16* lnbC = (bf16*)(r0 + 33554432);        // 16777216 B
  bf16* xnbQ = (bf16*)(r0 + 50331648);        // 33554432 B
  bf16* xnbC = (bf16*)(r0 + 83886080);        // 16777216 B
  bf16* hQ   = (bf16*)r0;                     // 67108864 B (NQ x 256)
  bf16* hC   = (bf16*)(r0 + 67108864);        // 33554432 B (NC x 256)
  bf16* projQ = (bf16*)alloc((size_t)NQn * 128 * 2);
  bf16* projC = (bf16*)alloc((size_t)NCn * 128 * 2);
  bf16* msgQ  = (bf16*)alloc((size_t)NQn * 128 * 2);
  bf16* msgC  = (bf16*)alloc((size_t)NCn * 128 * 2);
  bf16* WresQt = (bf16*)alloc(128 * 128 * 2);
  bf16* WresCt = (bf16*)alloc(128 * 128 * 2);
  bf16* WrelQCt = (bf16*)alloc(128 * 128 * 2);
  bf16* WrelCQt = (bf16*)alloc(128 * 128 * 2);
  bf16* W1Qt = (bf16*)alloc(256 * 256 * 2);
  bf16* W1Ct = (bf16*)alloc(256 * 256 * 2);
  bf16* W2Qt = (bf16*)alloc(128 * 256 * 2);
  bf16* W2Ct = (bf16*)alloc(128 * 256 * 2);
  int* offsQC = (int*)alloc((size_t)NCn * 4);
  int* curQC  = (int*)alloc((size_t)NCn * 4);
  int* offsCQ = (int*)alloc((size_t)NQn * 4);
  int* curCQ  = (int*)alloc((size_t)NQn * 4);
  int* csrQC  = (int*)alloc((size_t)En * 4);
  int* csrCQ  = (int*)alloc((size_t)En * 4);
  int* bsumQC = (int*)alloc(1024);
  int* bsumCQ = (int*)alloc(1024);

  float* outQ = (float*)d_out;
  float* outC = (float*)d_out + (size_t)NQn * 128;

  // 1. weight transpose+cast
  wtrans_all<<<dim3(256, 8), 256, 0, stream>>>(
      Wres_Q, WresQt, Wres_C, WresCt, Wrel_QC, WrelQCt, Wrel_CQ, WrelCQt,
      W1_Q, W1Qt, W1_C, W1Ct, W2_Q, W2Qt, W2_C, W2Ct);

  // 2. LayerNorm -> bf16
  ln_kernel<<<NQn / 4, 256, 0, stream>>>(H_Q, ln_g_Q, ln_b_Q, lnbQ, NQn);
  ln_kernel<<<NCn / 4, 256, 0, stream>>>(H_C, ln_g_C, ln_b_C, lnbC, NCn);

  // 3. proj = LN(H) @ Wres  (bf16 out)
  gemm_kernel<ASRC_BF16, EPI_BF16, 1><<<dim3(NQn / 128, 1), 256, 0, stream>>>(
      lnbQ, nullptr, WresQt, nullptr, nullptr, nullptr, projQ, nullptr, 128, 0, 128);
  gemm_kernel<ASRC_BF16, EPI_BF16, 1><<<dim3(NCn / 128, 1), 256, 0, stream>>>(
      lnbC, nullptr, WresCt, nullptr, nullptr, nullptr, projC, nullptr, 128, 0, 128);

  // 4. Xn = (H @ Wrel) * invsqrt(deg_src)  (bf16 out)
  gemm_kernel<ASRC_F32, EPI_RSCL, 1><<<dim3(NQn / 128, 1), 256, 0, stream>>>(
      H_Q, nullptr, WrelQCt, nullptr, deg_QC_src, nullptr, xnbQ, nullptr, 128, 0, 128);
  gemm_kernel<ASRC_F32, EPI_RSCL, 1><<<dim3(NCn / 128, 1), 256, 0, stream>>>(
      H_C, nullptr, WrelCQt, nullptr, deg_CQ_src, nullptr, xnbC, nullptr, 128, 0, 128);

  // 5. CSR build for both relations
  hipMemsetAsync(curQC, 0, (size_t)NCn * 4, stream);
  hipMemsetAsync(curCQ, 0, (size_t)NQn * 4, stream);
  hist_kernel<<<En / 256, 256, 0, stream>>>(eQC_dst, curQC);
  hist_kernel<<<En / 256, 256, 0, stream>>>(eCQ_dst, curCQ);
  scan_local<<<NCn / 1024, 1024, 0, stream>>>(curQC, offsQC, bsumQC);
  scan_local<<<NQn / 1024, 1024, 0, stream>>>(curCQ, offsCQ, bsumCQ);
  scan_bsum<<<1, 64, 0, stream>>>(bsumQC, NCn / 1024);
  scan_bsum<<<1, 64, 0, stream>>>(bsumCQ, NQn / 1024);
  scan_add<<<NCn / 256, 256, 0, stream>>>(offsQC, curQC, bsumQC);
  scan_add<<<NQn / 256, 256, 0, stream>>>(offsCQ, curCQ, bsumCQ);
  fill_kernel<<<En / 256, 256, 0, stream>>>(eQC_src, eQC_dst, curQC, csrQC);
  fill_kernel<<<En / 256, 256, 0, stream>>>(eCQ_src, eCQ_dst, curCQ, csrCQ);

  // 6. gather (scatter-free SpMM): msgC from xnbQ, msgQ from xnbC
  gather_kernel<<<NCn / 4, 256, 0, stream>>>(xnbQ, csrQC, offsQC, deg_QC_dst,
                                             gate_QC, msgC, NCn);
  gather_kernel<<<NQn / 4, 256, 0, stream>>>(xnbC, csrCQ, offsCQ, deg_CQ_dst,
                                             gate_CQ, msgQ, NQn);

  // 7. MLP layer 1: h = gelu([proj | msg] @ W1 + b1)   (writes over R0 — LN/Xn dead)
  gemm_kernel<ASRC_BF16, EPI_GELU, 2><<<dim3(NQn / 128, 2), 256, 0, stream>>>(
      projQ, msgQ, W1Qt, b1_Q, nullptr, nullptr, hQ, nullptr, 128, 0, 256);
  gemm_kernel<ASRC_BF16, EPI_GELU, 2><<<dim3(NCn / 128, 2), 256, 0, stream>>>(
      projC, msgC, W1Ct, b1_C, nullptr, nullptr, hC, nullptr, 128, 0, 256);

  // 8. MLP layer 2 + residual: out = proj + h @ W2 + b2  (f32 out)
  gemm_kernel<ASRC_BF16, EPI_RES, 2><<<dim3(NQn / 128, 1), 256, 0, stream>>>(
      hQ, hQ, W2Qt, b2_Q, nullptr, projQ, nullptr, outQ, 256, 128, 128);
  gemm_kernel<ASRC_BF16, EPI_RES, 2><<<dim3(NCn / 128, 1), 256, 0, stream>>>(
      hC, hC, W2Ct, b2_C, nullptr, projC, nullptr, outC, 256, 128, 128);
}

// Round 2
// 490.783 us; speedup vs baseline: 1.3374x; 1.3374x over previous
//
#include <hip/hip_runtime.h>
#include <stdint.h>

// Problem sizes (fixed by the reference)
#define NQn 131072
#define NCn 65536
#define En  1048576
// D = 128, HID = 256

typedef __bf16 bf16;
typedef __bf16 bf16x2 __attribute__((ext_vector_type(2)));
typedef __bf16 bf16x4 __attribute__((ext_vector_type(4)));
typedef __bf16 bf16x8 __attribute__((ext_vector_type(8)));
typedef float  f32x4  __attribute__((ext_vector_type(4)));

// ---------------------------------------------------------------------------
// Weight transpose + bf16 cast: Wt[m*K+k] = bf16(W[k*M+m])
// ---------------------------------------------------------------------------
__global__ void wtrans_all(
    const float* __restrict__ w0, bf16* __restrict__ t0,
    const float* __restrict__ w1, bf16* __restrict__ t1,
    const float* __restrict__ w2, bf16* __restrict__ t2,
    const float* __restrict__ w3, bf16* __restrict__ t3,
    const float* __restrict__ w4, bf16* __restrict__ t4,
    const float* __restrict__ w5, bf16* __restrict__ t5,
    const float* __restrict__ w6, bf16* __restrict__ t6,
    const float* __restrict__ w7, bf16* __restrict__ t7) {
  const float* W; bf16* T; int K, M;
  switch (blockIdx.y) {
    case 0: W = w0; T = t0; K = 128; M = 128; break;  // Wres_Q
    case 1: W = w1; T = t1; K = 128; M = 128; break;  // Wres_C
    case 2: W = w2; T = t2; K = 128; M = 128; break;  // Wrel_QC
    case 3: W = w3; T = t3; K = 128; M = 128; break;  // Wrel_CQ
    case 4: W = w4; T = t4; K = 256; M = 256; break;  // W1_Q
    case 5: W = w5; T = t5; K = 256; M = 256; break;  // W1_C
    case 6: W = w6; T = t6; K = 256; M = 128; break;  // W2_Q
    default: W = w7; T = t7; K = 256; M = 128; break; // W2_C
  }
  int t = blockIdx.x * 256 + threadIdx.x;
  if (t >= K * M) return;
  int m = t % M, k = t / M;
  T[m * K + k] = (bf16)W[k * M + m];
}

// ---------------------------------------------------------------------------
// Row LayerNorm -> bf16. One wave (64 lanes) per row, 2 elems/lane.
// ---------------------------------------------------------------------------
__global__ __launch_bounds__(256) void ln_kernel(
    const float* __restrict__ H, const float* __restrict__ g,
    const float* __restrict__ b, bf16* __restrict__ out, int nrows) {
  int row = blockIdx.x * 4 + (threadIdx.x >> 6);
  if (row >= nrows) return;
  int lane = threadIdx.x & 63;
  const float* rp = H + (size_t)row * 128;
  float2 v = *(const float2*)(rp + lane * 2);
  float s = v.x + v.y;
  #pragma unroll
  for (int o = 32; o; o >>= 1) s += __shfl_xor(s, o, 64);
  float mean = s * (1.0f / 128.0f);
  float dx = v.x - mean, dy = v.y - mean;
  float q = dx * dx + dy * dy;
  #pragma unroll
  for (int o = 32; o; o >>= 1) q += __shfl_xor(q, o, 64);
  float rs = rsqrtf(q * (1.0f / 128.0f) + 1e-5f);
  float2 gg = *(const float2*)(g + lane * 2);
  float2 bb = *(const float2*)(b + lane * 2);
  bf16x2 r;
  r[0] = (bf16)(dx * rs * gg.x + bb.x);
  r[1] = (bf16)(dy * rs * gg.y + bb.y);
  *(bf16x2*)(out + (size_t)row * 128 + lane * 2) = r;
}

// ---------------------------------------------------------------------------
// Generic 128x128-tile bf16 MFMA GEMM (see R0 notes). Epilogues:
// 0 store bf16; 1 row-scale store bf16; 2 +bias GELU store bf16;
// 3 +bias +resid store f32. LDS XOR-swizzled both sides.
// ---------------------------------------------------------------------------
#define ASRC_BF16 0
#define ASRC_F32  1
#define EPI_BF16  0
#define EPI_RSCL  1
#define EPI_GELU  2
#define EPI_RES   3

template <int ASRC, int EPI, int NK>
__global__ __launch_bounds__(256, 2) void gemm_kernel(
    const void* __restrict__ A0, const void* __restrict__ A1,
    const bf16* __restrict__ Bt, const float* __restrict__ bias,
    const float* __restrict__ rowscale, const bf16* __restrict__ resid,
    bf16* __restrict__ outB, float* __restrict__ outF,
    int ldA, int kOff, int ldOut) {
  __shared__ __align__(16) unsigned char lds[65536];
  const int tid = threadIdx.x;
  const int row0 = blockIdx.x * 128;
  const int col0 = blockIdx.y * 128;
  const int wid = tid >> 6, lane = tid & 63;
  const int wrow = (wid >> 1) * 64, wcol = (wid & 1) * 64;

  f32x4 acc[4][4] = {};

  #pragma unroll
  for (int kc = 0; kc < NK; ++kc) {
    if (kc) __syncthreads();
    const void* ap = (kc == 0) ? A0 : A1;
    const int kofs = kc * kOff;
    if (ASRC == ASRC_F32) {
      const float* Af = (const float*)ap;
      #pragma unroll
      for (int it = 0; it < 16; ++it) {
        int lin = it * 256 + tid;
        int r = lin >> 5;
        int c = (lin & 31) * 4;
        float4 v = *(const float4*)(Af + (size_t)(row0 + r) * ldA + kofs + c);
        bf16x4 w;
        w[0] = (bf16)v.x; w[1] = (bf16)v.y; w[2] = (bf16)v.z; w[3] = (bf16)v.w;
        *(bf16x4*)(lds + r * 256 + ((c * 2) ^ ((r & 7) << 4))) = w;
      }
    } else {
      const bf16* Ab = (const bf16*)ap;
      #pragma unroll
      for (int it = 0; it < 8; ++it) {
        int lin = it * 256 + tid;
        int r = lin >> 4;
        int cb = (lin & 15) * 16;
        bf16x8 v = *(const bf16x8*)((const char*)Ab +
                    ((size_t)(row0 + r) * ldA + kofs) * 2 + cb);
        *(bf16x8*)(lds + r * 256 + (cb ^ ((r & 7) << 4))) = v;
      }
    }
    #pragma unroll
    for (int it = 0; it < 8; ++it) {
      int lin = it * 256 + tid;
      int r = lin >> 4;
      int cb = (lin & 15) * 16;
      bf16x8 v = *(const bf16x8*)((const char*)Bt +
                  ((size_t)(col0 + r) * (NK * 128) + kc * 128) * 2 + cb);
      *(bf16x8*)(lds + 32768 + r * 256 + (cb ^ ((r & 7) << 4))) = v;
    }
    __syncthreads();
    #pragma unroll
    for (int kk = 0; kk < 4; ++kk) {
      bf16x8 af[4], bfv[4];
      const int kb = kk * 64 + (lane >> 4) * 16;
      #pragma unroll
      for (int fr = 0; fr < 4; ++fr) {
        int ar = wrow + fr * 16 + (lane & 15);
        af[fr] = *(const bf16x8*)(lds + ar * 256 + (kb ^ ((ar & 7) << 4)));
      }
      #pragma unroll
      for (int fc = 0; fc < 4; ++fc) {
        int br = wcol + fc * 16 + (lane & 15);
        bfv[fc] = *(const bf16x8*)(lds + 32768 + br * 256 + (kb ^ ((br & 7) << 4)));
      }
      #pragma unroll
      for (int fr = 0; fr < 4; ++fr)
        #pragma unroll
        for (int fc = 0; fc < 4; ++fc)
          acc[fr][fc] = __builtin_amdgcn_mfma_f32_16x16x32_bf16(
              af[fr], bfv[fc], acc[fr][fc], 0, 0, 0);
    }
  }

  const int rbase = row0 + wrow + (lane >> 4) * 4;
  const int cbase = col0 + wcol + (lane & 15);
  #pragma unroll
  for (int fr = 0; fr < 4; ++fr) {
    float rs[4];
    if (EPI == EPI_RSCL) {
      #pragma unroll
      for (int r = 0; r < 4; ++r) {
        float dv = rowscale[rbase + fr * 16 + r];
        rs[r] = dv > 0.f ? rsqrtf(dv) : 0.f;
      }
    }
    #pragma unroll
    for (int fc = 0; fc < 4; ++fc) {
      const int col = cbase + fc * 16;
      float bv = (EPI == EPI_GELU || EPI == EPI_RES) ? bias[col] : 0.f;
      #pragma unroll
      for (int r = 0; r < 4; ++r) {
        const int row = rbase + fr * 16 + r;
        float x = acc[fr][fc][r];
        if (EPI == EPI_BF16) {
          outB[(size_t)row * ldOut + col] = (bf16)x;
        } else if (EPI == EPI_RSCL) {
          outB[(size_t)row * ldOut + col] = (bf16)(x * rs[r]);
        } else if (EPI == EPI_GELU) {
          x += bv;
          x = 0.5f * x * (1.f + erff(x * 0.70710678118f));
          outB[(size_t)row * ldOut + col] = (bf16)x;
        } else {
          x += bv + (float)resid[(size_t)row * 128 + col];
          outF[(size_t)row * 128 + col] = x;
        }
      }
    }
  }
}

// ---------------------------------------------------------------------------
// Offsets from deg (the histogram is an input!): 2-level exclusive scan.
// ---------------------------------------------------------------------------
__global__ __launch_bounds__(1024) void scan_local(
    const float* __restrict__ deg, int* __restrict__ offs, int* __restrict__ bsum) {
  __shared__ int s[1024];
  int i = blockIdx.x * 1024 + threadIdx.x;
  int v = (int)(deg[i] + 0.5f);
  s[threadIdx.x] = v;
  __syncthreads();
  for (int o = 1; o < 1024; o <<= 1) {
    int x = (threadIdx.x >= o) ? s[threadIdx.x - o] : 0;
    __syncthreads();
    s[threadIdx.x] += x;
    __syncthreads();
  }
  offs[i] = s[threadIdx.x] - v;
  if (threadIdx.x == 1023) bsum[blockIdx.x] = s[1023];
}

__global__ void scan_bsum(int* bsum, int nb) {
  if (threadIdx.x == 0 && blockIdx.x == 0) {
    int run = 0;
    for (int j = 0; j < nb; ++j) { int t = bsum[j]; bsum[j] = run; run += t; }
  }
}

__global__ void scan_add(int* __restrict__ offs, const int* __restrict__ bsum) {
  int i = blockIdx.x * 256 + threadIdx.x;
  offs[i] += bsum[i >> 10];
}

// gcur[b] = offs[b*256] for both relations; write sentinels offs[N] = E
__global__ void init_gcur(const int* __restrict__ offsQC, int* __restrict__ gcurQC,
                          int* __restrict__ offsQCs,
                          const int* __restrict__ offsCQ, int* __restrict__ gcurCQ,
                          int* __restrict__ offsCQs) {
  int t = blockIdx.x * 256 + threadIdx.x;
  if (t < 256) gcurQC[t] = offsQC[t * 256];
  if (t < 512) gcurCQ[t] = offsCQ[t * 256];
  if (t == 0) { offsQCs[NCn] = En; offsCQs[NQn] = En; }
}

// ---------------------------------------------------------------------------
// Bucketed CSR build. Bucket = dst >> 8 (256 dsts / bucket).
// Pass A: partition (src,dst) pairs into bucket-grouped ebuf, dense writes.
// ---------------------------------------------------------------------------
#define CHUNK 4096

template <int NB>
__global__ __launch_bounds__(256) void bucketA(
    const int* __restrict__ esrc, const int* __restrict__ edst,
    int* __restrict__ gcur, uint2* __restrict__ ebuf) {
  __shared__ int lcount[NB], lexcl[NB], lbase[NB], lofs[NB];
  __shared__ int ss[256];
  __shared__ uint2 stage[CHUNK];
  const int t = threadIdx.x;
  for (int b = t; b < NB; b += 256) lcount[b] = 0;
  __syncthreads();
  const int e0 = blockIdx.x * CHUNK;
  uint2 ed[16];
  #pragma unroll
  for (int j = 0; j < 16; ++j) {
    int e = e0 + j * 256 + t;
    ed[j].x = (unsigned)esrc[e];
    ed[j].y = (unsigned)edst[e];
    atomicAdd(&lcount[ed[j].y >> 8], 1);
  }
  __syncthreads();
  // exclusive scan of lcount[NB] with 256 threads (NB = 256 or 512)
  int c0, c1 = 0, mysum;
  if (NB == 512) { c0 = lcount[2 * t]; c1 = lcount[2 * t + 1]; mysum = c0 + c1; }
  else           { c0 = lcount[t]; mysum = c0; }
  ss[t] = mysum;
  __syncthreads();
  for (int o = 1; o < 256; o <<= 1) {
    int x = (t >= o) ? ss[t - o] : 0;
    __syncthreads();
    ss[t] += x;
    __syncthreads();
  }
  int base = ss[t] - mysum;
  if (NB == 512) { lexcl[2 * t] = base; lexcl[2 * t + 1] = base + c0; }
  else           { lexcl[t] = base; }
  __syncthreads();
  for (int b = t; b < NB; b += 256) {
    lbase[b] = atomicAdd(&gcur[b], lcount[b]);
    lofs[b]  = lexcl[b];
  }
  __syncthreads();
  #pragma unroll
  for (int j = 0; j < 16; ++j) {
    int b = ed[j].y >> 8;
    int p = atomicAdd(&lofs[b], 1);
    stage[p] = ed[j];
  }
  __syncthreads();
  for (int i = t; i < CHUNK; i += 256) {
    uint2 v = stage[i];
    int b = v.y >> 8;
    ebuf[lbase[b] + (i - lexcl[b])] = v;
  }
}

// Pass B: one block per bucket; csr writes land in a hot ~8-16KB window.
__global__ __launch_bounds__(256) void bucketB(
    const uint2* __restrict__ ebuf, const int* __restrict__ goffs,
    int* __restrict__ csr) {
  __shared__ int lcur[256];
  const int b = blockIdx.x;
  lcur[threadIdx.x] = 0;
  __syncthreads();
  const int start = goffs[b * 256];
  const int end   = goffs[(b + 1) * 256];
  for (int i = start + threadIdx.x; i < end; i += 256) {
    uint2 v = ebuf[i];
    int p = atomicAdd(&lcur[v.y & 255], 1);
    csr[goffs[v.y] + p] = (int)v.x;
  }
}

// ---------------------------------------------------------------------------
// Gather: one wave per dst row; msg[d] = (sum_src Xn[src]) * invsqrt(deg_dst)*gate
// ---------------------------------------------------------------------------
__global__ __launch_bounds__(256) void gather_kernel(
    const bf16* __restrict__ Xn, const int* __restrict__ csr,
    const int* __restrict__ offs, const float* __restrict__ degdst,
    const float* __restrict__ gate, bf16* __restrict__ msg, int ndst) {
  int d = blockIdx.x * 4 + (threadIdx.x >> 6);
  if (d >= ndst) return;
  int lane = threadIdx.x & 63;
  float dv = degdst[d];
  int cnt = (int)(dv + 0.5f);
  int start = offs[d];
  float ax = 0.f, ay = 0.f;
  int i = 0;
  for (; i + 2 <= cnt; i += 2) {
    int s0 = csr[start + i], s1 = csr[start + i + 1];
    bf16x2 v0 = *(const bf16x2*)(Xn + (size_t)s0 * 128 + lane * 2);
    bf16x2 v1 = *(const bf16x2*)(Xn + (size_t)s1 * 128 + lane * 2);
    ax += (float)v0[0] + (float)v1[0];
    ay += (float)v0[1] + (float)v1[1];
  }
  if (i < cnt) {
    int s0 = csr[start + i];
    bf16x2 v0 = *(const bf16x2*)(Xn + (size_t)s0 * 128 + lane * 2);
    ax += (float)v0[0];
    ay += (float)v0[1];
  }
  float sc = (dv > 0.f ? rsqrtf(dv) : 0.f) * gate[0];
  bf16x2 r;
  r[0] = (bf16)(ax * sc);
  r[1] = (bf16)(ay * sc);
  *(bf16x2*)(msg + (size_t)d * 128 + lane * 2) = r;
}

// ---------------------------------------------------------------------------
extern "C" void kernel_launch(void* const* d_in, const int* in_sizes, int n_in,
                              void* d_out, int out_size, void* d_ws, size_t ws_size,
                              hipStream_t stream) {
  const float* H_Q        = (const float*)d_in[0];
  const float* H_C        = (const float*)d_in[1];
  const int*   eQC_src    = (const int*)d_in[2];
  const int*   eQC_dst    = (const int*)d_in[3];
  const int*   eCQ_src    = (const int*)d_in[4];
  const int*   eCQ_dst    = (const int*)d_in[5];
  const float* deg_QC_src = (const float*)d_in[6];
  const float* deg_QC_dst = (const float*)d_in[7];
  const float* deg_CQ_src = (const float*)d_in[8];
  const float* deg_CQ_dst = (const float*)d_in[9];
  const float* ln_g_Q     = (const float*)d_in[10];
  const float* ln_b_Q     = (const float*)d_in[11];
  const float* Wres_Q     = (const float*)d_in[12];
  const float* ln_g_C     = (const float*)d_in[13];
  const float* ln_b_C     = (const float*)d_in[14];
  const float* Wres_C     = (const float*)d_in[15];
  const float* Wrel_QC    = (const float*)d_in[16];
  const float* Wrel_CQ    = (const float*)d_in[17];
  const float* gate_QC    = (const float*)d_in[18];
  const float* gate_CQ    = (const float*)d_in[19];
  const float* W1_Q       = (const float*)d_in[20];
  const float* b1_Q       = (const float*)d_in[21];
  const float* W2_Q       = (const float*)d_in[22];
  const float* b2_Q       = (const float*)d_in[23];
  const float* W1_C       = (const float*)d_in[24];
  const float* b1_C       = (const float*)d_in[25];
  const float* W2_C       = (const float*)d_in[26];
  const float* b2_C       = (const float*)d_in[27];

  char* ws = (char*)d_ws;
  size_t o = 0;
  auto alloc = [&](size_t bytes) -> char* {
    char* p = ws + o;
    o += (bytes + 255) & ~(size_t)255;
    return p;
  };
  // R0 overlay: {lnbQ, lnbC, xnbQ, xnbC} (phase 1-2) == {hQ, hC} (phase 3)
  char* r0 = alloc(100663296);
  bf16* lnbQ = (bf16*)r0;                     // 33554432 B
  bf16* lnbC = (bf16*)(r0 + 33554432);        // 16777216 B
  bf16* xnbQ = (bf16*)(r0 + 50331648);        // 33554432 B
  bf16* xnbC = (bf16*)(r0 + 83886080);        // 16777216 B
  bf16* hQ   = (bf16*)r0;                     // 67108864 B (NQ x 256)
  bf16* hC   = (bf16*)(r0 + 67108864);        // 33554432 B (NC x 256)
  bf16* projQ = (bf16*)alloc((size_t)NQn * 128 * 2);
  bf16* projC = (bf16*)alloc((size_t)NCn * 128 * 2);
  char* msgR  = alloc((size_t)(NQn + NCn) * 128 * 2);
  bf16* msgQ  = (bf16*)msgR;                  // 33554432 B
  bf16* msgC  = (bf16*)(msgR + (size_t)NQn * 128 * 2);
  // ebuf overlays msgQ (dead until gather; bucketB finishes first)
  uint2* ebufQC = (uint2*)msgR;               // 8 MB
  uint2* ebufCQ = (uint2*)(msgR + 8388608);   // 8 MB
  bf16* WresQt = (bf16*)alloc(128 * 128 * 2);
  bf16* WresCt = (bf16*)alloc(128 * 128 * 2);
  bf16* WrelQCt = (bf16*)alloc(128 * 128 * 2);
  bf16* WrelCQt = (bf16*)alloc(128 * 128 * 2);
  bf16* W1Qt = (bf16*)alloc(256 * 256 * 2);
  bf16* W1Ct = (bf16*)alloc(256 * 256 * 2);
  bf16* W2Qt = (bf16*)alloc(128 * 256 * 2);
  bf16* W2Ct = (bf16*)alloc(128 * 256 * 2);
  int* offsQC = (int*)alloc((size_t)(NCn + 1) * 4);
  int* offsCQ = (int*)alloc((size_t)(NQn + 1) * 4);
  int* csrQC  = (int*)alloc((size_t)En * 4);
  int* csrCQ  = (int*)alloc((size_t)En * 4);
  int* bsumQC = (int*)alloc(1024);
  int* bsumCQ = (int*)alloc(1024);
  int* gcurQC = (int*)alloc(256 * 4);
  int* gcurCQ = (int*)alloc(512 * 4);

  float* outQ = (float*)d_out;
  float* outC = (float*)d_out + (size_t)NQn * 128;

  // 1. weight transpose+cast
  wtrans_all<<<dim3(256, 8), 256, 0, stream>>>(
      Wres_Q, WresQt, Wres_C, WresCt, Wrel_QC, WrelQCt, Wrel_CQ, WrelCQt,
      W1_Q, W1Qt, W1_C, W1Ct, W2_Q, W2Qt, W2_C, W2Ct);

  // 2. LayerNorm -> bf16
  ln_kernel<<<NQn / 4, 256, 0, stream>>>(H_Q, ln_g_Q, ln_b_Q, lnbQ, NQn);
  ln_kernel<<<NCn / 4, 256, 0, stream>>>(H_C, ln_g_C, ln_b_C, lnbC, NCn);

  // 3. proj = LN(H) @ Wres  (bf16 out)
  gemm_kernel<ASRC_BF16, EPI_BF16, 1><<<dim3(NQn / 128, 1), 256, 0, stream>>>(
      lnbQ, nullptr, WresQt, nullptr, nullptr, nullptr, projQ, nullptr, 128, 0, 128);
  gemm_kernel<ASRC_BF16, EPI_BF16, 1><<<dim3(NCn / 128, 1), 256, 0, stream>>>(
      lnbC, nullptr, WresCt, nullptr, nullptr, nullptr, projC, nullptr, 128, 0, 128);

  // 4. Xn = (H @ Wrel) * invsqrt(deg_src)  (bf16 out)
  gemm_kernel<ASRC_F32, EPI_RSCL, 1><<<dim3(NQn / 128, 1), 256, 0, stream>>>(
      H_Q, nullptr, WrelQCt, nullptr, deg_QC_src, nullptr, xnbQ, nullptr, 128, 0, 128);
  gemm_kernel<ASRC_F32, EPI_RSCL, 1><<<dim3(NCn / 128, 1), 256, 0, stream>>>(
      H_C, nullptr, WrelCQt, nullptr, deg_CQ_src, nullptr, xnbC, nullptr, 128, 0, 128);

  // 5. CSR build: deg-scan -> offs; bucketed partition -> ebuf; bucket fill -> csr
  scan_local<<<NCn / 1024, 1024, 0, stream>>>(deg_QC_dst, offsQC, bsumQC);
  scan_local<<<NQn / 1024, 1024, 0, stream>>>(deg_CQ_dst, offsCQ, bsumCQ);
  scan_bsum<<<1, 64, 0, stream>>>(bsumQC, NCn / 1024);
  scan_bsum<<<1, 64, 0, stream>>>(bsumCQ, NQn / 1024);
  scan_add<<<NCn / 256, 256, 0, stream>>>(offsQC, bsumQC);
  scan_add<<<NQn / 256, 256, 0, stream>>>(offsCQ, bsumCQ);
  init_gcur<<<2, 256, 0, stream>>>(offsQC, gcurQC, offsQC, offsCQ, gcurCQ, offsCQ);
  bucketA<256><<<En / CHUNK, 256, 0, stream>>>(eQC_src, eQC_dst, gcurQC, ebufQC);
  bucketA<512><<<En / CHUNK, 256, 0, stream>>>(eCQ_src, eCQ_dst, gcurCQ, ebufCQ);
  bucketB<<<NCn / 256, 256, 0, stream>>>(ebufQC, offsQC, csrQC);
  bucketB<<<NQn / 256, 256, 0, stream>>>(ebufCQ, offsCQ, csrCQ);

  // 6. gather (scatter-free SpMM): msgC from xnbQ, msgQ from xnbC
  gather_kernel<<<NCn / 4, 256, 0, stream>>>(xnbQ, csrQC, offsQC, deg_QC_dst,
                                             gate_QC, msgC, NCn);
  gather_kernel<<<NQn / 4, 256, 0, stream>>>(xnbC, csrCQ, offsCQ, deg_CQ_dst,
                                             gate_CQ, msgQ, NQn);

  // 7. MLP layer 1: h = gelu([proj | msg] @ W1 + b1)   (writes over R0 — LN/Xn dead)
  gemm_kernel<ASRC_BF16, EPI_GELU, 2><<<dim3(NQn / 128, 2), 256, 0, stream>>>(
      projQ, msgQ, W1Qt, b1_Q, nullptr, nullptr, hQ, nullptr, 128, 0, 256);
  gemm_kernel<ASRC_BF16, EPI_GELU, 2><<<dim3(NCn / 128, 2), 256, 0, stream>>>(
      projC, msgC, W1Ct, b1_C, nullptr, nullptr, hC, nullptr, 128, 0, 256);

  // 8. MLP layer 2 + residual: out = proj + h @ W2 + b2  (f32 out)
  gemm_kernel<ASRC_BF16, EPI_RES, 2><<<dim3(NQn / 128, 1), 256, 0, stream>>>(
      hQ, hQ, W2Qt, b2_Q, nullptr, projQ, nullptr, outQ, 256, 128, 128);
  gemm_kernel<ASRC_BF16, EPI_RES, 2><<<dim3(NCn / 128, 1), 256, 0, stream>>>(
      hC, hC, W2Ct, b2_C, nullptr, projC, nullptr, outC, 256, 128, 128);
}

// Round 3
// 420.213 us; speedup vs baseline: 1.5620x; 1.1679x over previous
//
#include <hip/hip_runtime.h>
#include <stdint.h>

// Problem sizes (fixed by the reference)
#define NQn 131072
#define NCn 65536
#define En  1048576
// D = 128, HID = 256

typedef __bf16 bf16;
typedef __bf16 bf16x2 __attribute__((ext_vector_type(2)));
typedef __bf16 bf16x4 __attribute__((ext_vector_type(4)));
typedef __bf16 bf16x8 __attribute__((ext_vector_type(8)));
typedef float  f32x4  __attribute__((ext_vector_type(4)));

// ---------------------------------------------------------------------------
// Weight transpose + bf16 cast: Wt[m*K+k] = bf16(W[k*M+m])
// ---------------------------------------------------------------------------
__global__ void wtrans_all(
    const float* __restrict__ w0, bf16* __restrict__ t0,
    const float* __restrict__ w1, bf16* __restrict__ t1,
    const float* __restrict__ w2, bf16* __restrict__ t2,
    const float* __restrict__ w3, bf16* __restrict__ t3,
    const float* __restrict__ w4, bf16* __restrict__ t4,
    const float* __restrict__ w5, bf16* __restrict__ t5,
    const float* __restrict__ w6, bf16* __restrict__ t6,
    const float* __restrict__ w7, bf16* __restrict__ t7) {
  const float* W; bf16* T; int K, M;
  switch (blockIdx.y) {
    case 0: W = w0; T = t0; K = 128; M = 128; break;  // Wres_Q
    case 1: W = w1; T = t1; K = 128; M = 128; break;  // Wres_C
    case 2: W = w2; T = t2; K = 128; M = 128; break;  // Wrel_QC
    case 3: W = w3; T = t3; K = 128; M = 128; break;  // Wrel_CQ
    case 4: W = w4; T = t4; K = 256; M = 256; break;  // W1_Q
    case 5: W = w5; T = t5; K = 256; M = 256; break;  // W1_C
    case 6: W = w6; T = t6; K = 256; M = 128; break;  // W2_Q
    default: W = w7; T = t7; K = 256; M = 128; break; // W2_C
  }
  int t = blockIdx.x * 256 + threadIdx.x;
  if (t >= K * M) return;
  int m = t % M, k = t / M;
  T[m * K + k] = (bf16)W[k * M + m];
}

// ---------------------------------------------------------------------------
// Row LayerNorm -> bf16. One wave (64 lanes) per row, 2 elems/lane.
// ---------------------------------------------------------------------------
__global__ __launch_bounds__(256) void ln_kernel(
    const float* __restrict__ H, const float* __restrict__ g,
    const float* __restrict__ b, bf16* __restrict__ out, int nrows) {
  int row = blockIdx.x * 4 + (threadIdx.x >> 6);
  if (row >= nrows) return;
  int lane = threadIdx.x & 63;
  const float* rp = H + (size_t)row * 128;
  float2 v = *(const float2*)(rp + lane * 2);
  float s = v.x + v.y;
  #pragma unroll
  for (int o = 32; o; o >>= 1) s += __shfl_xor(s, o, 64);
  float mean = s * (1.0f / 128.0f);
  float dx = v.x - mean, dy = v.y - mean;
  float q = dx * dx + dy * dy;
  #pragma unroll
  for (int o = 32; o; o >>= 1) q += __shfl_xor(q, o, 64);
  float rs = rsqrtf(q * (1.0f / 128.0f) + 1e-5f);
  float2 gg = *(const float2*)(g + lane * 2);
  float2 bb = *(const float2*)(b + lane * 2);
  bf16x2 r;
  r[0] = (bf16)(dx * rs * gg.x + bb.x);
  r[1] = (bf16)(dy * rs * gg.y + bb.y);
  *(bf16x2*)(out + (size_t)row * 128 + lane * 2) = r;
}

// ---------------------------------------------------------------------------
// Generic 128x128-tile bf16 MFMA GEMM. Epilogues:
// 0 store bf16; 1 row-scale store bf16; 2 +bias tanh-GELU store bf16;
// 3 +bias +resid store f32. LDS XOR-swizzled both sides.
// ---------------------------------------------------------------------------
#define ASRC_BF16 0
#define ASRC_F32  1
#define EPI_BF16  0
#define EPI_RSCL  1
#define EPI_GELU  2
#define EPI_RES   3

template <int ASRC, int EPI, int NK>
__global__ __launch_bounds__(256, 2) void gemm_kernel(
    const void* __restrict__ A0, const void* __restrict__ A1,
    const bf16* __restrict__ Bt, const float* __restrict__ bias,
    const float* __restrict__ rowscale, const bf16* __restrict__ resid,
    bf16* __restrict__ outB, float* __restrict__ outF,
    int ldA, int kOff, int ldOut) {
  __shared__ __align__(16) unsigned char lds[65536];
  const int tid = threadIdx.x;
  const int row0 = blockIdx.x * 128;
  const int col0 = blockIdx.y * 128;
  const int wid = tid >> 6, lane = tid & 63;
  const int wrow = (wid >> 1) * 64, wcol = (wid & 1) * 64;

  f32x4 acc[4][4] = {};

  #pragma unroll
  for (int kc = 0; kc < NK; ++kc) {
    if (kc) __syncthreads();
    const void* ap = (kc == 0) ? A0 : A1;
    const int kofs = kc * kOff;
    if (ASRC == ASRC_F32) {
      const float* Af = (const float*)ap;
      #pragma unroll
      for (int it = 0; it < 16; ++it) {
        int lin = it * 256 + tid;
        int r = lin >> 5;
        int c = (lin & 31) * 4;
        float4 v = *(const float4*)(Af + (size_t)(row0 + r) * ldA + kofs + c);
        bf16x4 w;
        w[0] = (bf16)v.x; w[1] = (bf16)v.y; w[2] = (bf16)v.z; w[3] = (bf16)v.w;
        *(bf16x4*)(lds + r * 256 + ((c * 2) ^ ((r & 7) << 4))) = w;
      }
    } else {
      const bf16* Ab = (const bf16*)ap;
      #pragma unroll
      for (int it = 0; it < 8; ++it) {
        int lin = it * 256 + tid;
        int r = lin >> 4;
        int cb = (lin & 15) * 16;
        bf16x8 v = *(const bf16x8*)((const char*)Ab +
                    ((size_t)(row0 + r) * ldA + kofs) * 2 + cb);
        *(bf16x8*)(lds + r * 256 + (cb ^ ((r & 7) << 4))) = v;
      }
    }
    #pragma unroll
    for (int it = 0; it < 8; ++it) {
      int lin = it * 256 + tid;
      int r = lin >> 4;
      int cb = (lin & 15) * 16;
      bf16x8 v = *(const bf16x8*)((const char*)Bt +
                  ((size_t)(col0 + r) * (NK * 128) + kc * 128) * 2 + cb);
      *(bf16x8*)(lds + 32768 + r * 256 + (cb ^ ((r & 7) << 4))) = v;
    }
    __syncthreads();
    #pragma unroll
    for (int kk = 0; kk < 4; ++kk) {
      bf16x8 af[4], bfv[4];
      const int kb = kk * 64 + (lane >> 4) * 16;
      #pragma unroll
      for (int fr = 0; fr < 4; ++fr) {
        int ar = wrow + fr * 16 + (lane & 15);
        af[fr] = *(const bf16x8*)(lds + ar * 256 + (kb ^ ((ar & 7) << 4)));
      }
      #pragma unroll
      for (int fc = 0; fc < 4; ++fc) {
        int br = wcol + fc * 16 + (lane & 15);
        bfv[fc] = *(const bf16x8*)(lds + 32768 + br * 256 + (kb ^ ((br & 7) << 4)));
      }
      #pragma unroll
      for (int fr = 0; fr < 4; ++fr)
        #pragma unroll
        for (int fc = 0; fc < 4; ++fc)
          acc[fr][fc] = __builtin_amdgcn_mfma_f32_16x16x32_bf16(
              af[fr], bfv[fc], acc[fr][fc], 0, 0, 0);
    }
  }

  const int rbase = row0 + wrow + (lane >> 4) * 4;
  const int cbase = col0 + wcol + (lane & 15);
  #pragma unroll
  for (int fr = 0; fr < 4; ++fr) {
    float rs[4];
    if (EPI == EPI_RSCL) {
      #pragma unroll
      for (int r = 0; r < 4; ++r) {
        float dv = rowscale[rbase + fr * 16 + r];
        rs[r] = dv > 0.f ? rsqrtf(dv) : 0.f;
      }
    }
    #pragma unroll
    for (int fc = 0; fc < 4; ++fc) {
      const int col = cbase + fc * 16;
      float bv = (EPI == EPI_GELU || EPI == EPI_RES) ? bias[col] : 0.f;
      #pragma unroll
      for (int r = 0; r < 4; ++r) {
        const int row = rbase + fr * 16 + r;
        float x = acc[fr][fc][r];
        if (EPI == EPI_BF16) {
          outB[(size_t)row * ldOut + col] = (bf16)x;
        } else if (EPI == EPI_RSCL) {
          outB[(size_t)row * ldOut + col] = (bf16)(x * rs[r]);
        } else if (EPI == EPI_GELU) {
          x += bv;
          // tanh-form GELU: 0.5x(1+tanh(0.79788456(x+0.044715x^3)))
          // tanh(u) = 1 - 2/(exp(2u)+1)  (NaN-safe at +-inf)
          float u2 = 1.5957691216057308f * (x + 0.044715f * x * x * x);
          float e = __expf(u2);
          float th = 1.f - 2.f / (e + 1.f);
          x = 0.5f * x * (1.f + th);
          outB[(size_t)row * ldOut + col] = (bf16)x;
        } else {
          x += bv + (float)resid[(size_t)row * 128 + col];
          outF[(size_t)row * 128 + col] = x;
        }
      }
    }
  }
}

// ---------------------------------------------------------------------------
// Offsets from deg (the histogram is an input!): 2-level exclusive scan.
// One launch handles both relations (blockIdx < nbA -> QC, else CQ).
// ---------------------------------------------------------------------------
__global__ __launch_bounds__(1024) void scan_local2(
    const float* __restrict__ degA, int* __restrict__ offsA, int* __restrict__ bsumA,
    int nbA,
    const float* __restrict__ degB, int* __restrict__ offsB, int* __restrict__ bsumB) {
  __shared__ int s[1024];
  const float* deg; int* offs; int* bsum; int blk;
  if ((int)blockIdx.x < nbA) { deg = degA; offs = offsA; bsum = bsumA; blk = blockIdx.x; }
  else { deg = degB; offs = offsB; bsum = bsumB; blk = blockIdx.x - nbA; }
  int i = blk * 1024 + threadIdx.x;
  int v = (int)(deg[i] + 0.5f);
  s[threadIdx.x] = v;
  __syncthreads();
  for (int o = 1; o < 1024; o <<= 1) {
    int x = (threadIdx.x >= o) ? s[threadIdx.x - o] : 0;
    __syncthreads();
    s[threadIdx.x] += x;
    __syncthreads();
  }
  offs[i] = s[threadIdx.x] - v;
  if (threadIdx.x == 1023) bsum[blk] = s[1023];
}

__global__ void scan_bsum2(int* bsumA, int nbA, int* bsumB, int nbB) {
  if (threadIdx.x != 0) return;
  int* bsum = blockIdx.x == 0 ? bsumA : bsumB;
  int nb = blockIdx.x == 0 ? nbA : nbB;
  int run = 0;
  for (int j = 0; j < nb; ++j) { int t = bsum[j]; bsum[j] = run; run += t; }
}

// Add block sums, init per-bucket cursors from final offsets, write sentinels.
// grid = NQn/256 blocks (covers the larger array; QC guarded).
__global__ void scan_add2(int* __restrict__ offsQC, const int* __restrict__ bsumQC,
                          int* __restrict__ gcurQC,
                          int* __restrict__ offsCQ, const int* __restrict__ bsumCQ,
                          int* __restrict__ gcurCQ) {
  int i = blockIdx.x * 256 + threadIdx.x;
  if (i < NCn) {
    int v = offsQC[i] + bsumQC[i >> 10];
    offsQC[i] = v;
    if ((i & 255) == 0) gcurQC[i >> 8] = v;
  }
  int v = offsCQ[i] + bsumCQ[i >> 10];
  offsCQ[i] = v;
  if ((i & 255) == 0) gcurCQ[i >> 8] = v;
  if (i == 0) { offsQC[NCn] = En; offsCQ[NQn] = En; }
}

// ---------------------------------------------------------------------------
// Bucketed CSR build. Bucket = dst >> 8 (256 dsts / bucket).
// Pass A: partition (src,dst) pairs into bucket-grouped ebuf, dense writes.
// ---------------------------------------------------------------------------
#define CHUNK 4096

template <int NB>
__global__ __launch_bounds__(256) void bucketA(
    const int* __restrict__ esrc, const int* __restrict__ edst,
    int* __restrict__ gcur, uint2* __restrict__ ebuf) {
  __shared__ int lcount[NB], lexcl[NB], lbase[NB], lofs[NB];
  __shared__ int ss[256];
  __shared__ uint2 stage[CHUNK];
  const int t = threadIdx.x;
  for (int b = t; b < NB; b += 256) lcount[b] = 0;
  __syncthreads();
  const int e0 = blockIdx.x * CHUNK;
  uint2 ed[16];
  #pragma unroll
  for (int j = 0; j < 16; ++j) {
    int e = e0 + j * 256 + t;
    ed[j].x = (unsigned)esrc[e];
    ed[j].y = (unsigned)edst[e];
    atomicAdd(&lcount[ed[j].y >> 8], 1);
  }
  __syncthreads();
  int c0, c1 = 0, mysum;
  if (NB == 512) { c0 = lcount[2 * t]; c1 = lcount[2 * t + 1]; mysum = c0 + c1; }
  else           { c0 = lcount[t]; mysum = c0; }
  (void)c1;
  ss[t] = mysum;
  __syncthreads();
  for (int o = 1; o < 256; o <<= 1) {
    int x = (t >= o) ? ss[t - o] : 0;
    __syncthreads();
    ss[t] += x;
    __syncthreads();
  }
  int base = ss[t] - mysum;
  if (NB == 512) { lexcl[2 * t] = base; lexcl[2 * t + 1] = base + c0; }
  else           { lexcl[t] = base; }
  __syncthreads();
  for (int b = t; b < NB; b += 256) {
    lbase[b] = atomicAdd(&gcur[b], lcount[b]);
    lofs[b]  = lexcl[b];
  }
  __syncthreads();
  #pragma unroll
  for (int j = 0; j < 16; ++j) {
    int b = ed[j].y >> 8;
    int p = atomicAdd(&lofs[b], 1);
    stage[p] = ed[j];
  }
  __syncthreads();
  for (int i = t; i < CHUNK; i += 256) {
    uint2 v = stage[i];
    int b = v.y >> 8;
    ebuf[lbase[b] + (i - lexcl[b])] = v;
  }
}

// Pass B: one block per bucket; csr writes land in a hot ~8-16KB window.
__global__ __launch_bounds__(256) void bucketB(
    const uint2* __restrict__ ebuf, const int* __restrict__ goffs,
    int* __restrict__ csr) {
  __shared__ int lcur[256];
  const int b = blockIdx.x;
  lcur[threadIdx.x] = 0;
  __syncthreads();
  const int start = goffs[b * 256];
  const int end   = goffs[(b + 1) * 256];
  for (int i = start + threadIdx.x; i < end; i += 256) {
    uint2 v = ebuf[i];
    int p = atomicAdd(&lcur[v.y & 255], 1);
    csr[goffs[v.y] + p] = (int)v.x;
  }
}

// ---------------------------------------------------------------------------
// Gather: one wave per dst row, 4 edges in flight.
// msg[d] = (sum_src Xn[src]) * invsqrt(deg_dst) * gate
// ---------------------------------------------------------------------------
__global__ __launch_bounds__(256) void gather_kernel(
    const bf16* __restrict__ Xn, const int* __restrict__ csr,
    const int* __restrict__ offs, const float* __restrict__ degdst,
    const float* __restrict__ gate, bf16* __restrict__ msg, int ndst) {
  int d = blockIdx.x * 4 + (threadIdx.x >> 6);
  if (d >= ndst) return;
  int lane = threadIdx.x & 63;
  float dv = degdst[d];
  int cnt = (int)(dv + 0.5f);
  int start = offs[d];
  float ax0 = 0.f, ay0 = 0.f, ax1 = 0.f, ay1 = 0.f;
  int i = 0;
  for (; i + 4 <= cnt; i += 4) {
    int s0 = csr[start + i], s1 = csr[start + i + 1];
    int s2 = csr[start + i + 2], s3 = csr[start + i + 3];
    bf16x2 v0 = *(const bf16x2*)(Xn + (size_t)s0 * 128 + lane * 2);
    bf16x2 v1 = *(const bf16x2*)(Xn + (size_t)s1 * 128 + lane * 2);
    bf16x2 v2 = *(const bf16x2*)(Xn + (size_t)s2 * 128 + lane * 2);
    bf16x2 v3 = *(const bf16x2*)(Xn + (size_t)s3 * 128 + lane * 2);
    ax0 += (float)v0[0] + (float)v1[0];
    ay0 += (float)v0[1] + (float)v1[1];
    ax1 += (float)v2[0] + (float)v3[0];
    ay1 += (float)v2[1] + (float)v3[1];
  }
  for (; i < cnt; ++i) {
    int s0 = csr[start + i];
    bf16x2 v0 = *(const bf16x2*)(Xn + (size_t)s0 * 128 + lane * 2);
    ax0 += (float)v0[0];
    ay0 += (float)v0[1];
  }
  float ax = ax0 + ax1, ay = ay0 + ay1;
  float sc = (dv > 0.f ? rsqrtf(dv) : 0.f) * gate[0];
  bf16x2 r;
  r[0] = (bf16)(ax * sc);
  r[1] = (bf16)(ay * sc);
  *(bf16x2*)(msg + (size_t)d * 128 + lane * 2) = r;
}

// ---------------------------------------------------------------------------
extern "C" void kernel_launch(void* const* d_in, const int* in_sizes, int n_in,
                              void* d_out, int out_size, void* d_ws, size_t ws_size,
                              hipStream_t stream) {
  const float* H_Q        = (const float*)d_in[0];
  const float* H_C        = (const float*)d_in[1];
  const int*   eQC_src    = (const int*)d_in[2];
  const int*   eQC_dst    = (const int*)d_in[3];
  const int*   eCQ_src    = (const int*)d_in[4];
  const int*   eCQ_dst    = (const int*)d_in[5];
  const float* deg_QC_src = (const float*)d_in[6];
  const float* deg_QC_dst = (const float*)d_in[7];
  const float* deg_CQ_src = (const float*)d_in[8];
  const float* deg_CQ_dst = (const float*)d_in[9];
  const float* ln_g_Q     = (const float*)d_in[10];
  const float* ln_b_Q     = (const float*)d_in[11];
  const float* Wres_Q     = (const float*)d_in[12];
  const float* ln_g_C     = (const float*)d_in[13];
  const float* ln_b_C     = (const float*)d_in[14];
  const float* Wres_C     = (const float*)d_in[15];
  const float* Wrel_QC    = (const float*)d_in[16];
  const float* Wrel_CQ    = (const float*)d_in[17];
  const float* gate_QC    = (const float*)d_in[18];
  const float* gate_CQ    = (const float*)d_in[19];
  const float* W1_Q       = (const float*)d_in[20];
  const float* b1_Q       = (const float*)d_in[21];
  const float* W2_Q       = (const float*)d_in[22];
  const float* b2_Q       = (const float*)d_in[23];
  const float* W1_C       = (const float*)d_in[24];
  const float* b1_C       = (const float*)d_in[25];
  const float* W2_C       = (const float*)d_in[26];
  const float* b2_C       = (const float*)d_in[27];

  char* ws = (char*)d_ws;
  size_t o = 0;
  auto alloc = [&](size_t bytes) -> char* {
    char* p = ws + o;
    o += (bytes + 255) & ~(size_t)255;
    return p;
  };
  // R0 overlay: {lnbQ, lnbC, xnbQ, xnbC} (phase 1-2) == {hQ, hC} (phase 3)
  char* r0 = alloc(100663296);
  bf16* lnbQ = (bf16*)r0;                     // 33554432 B
  bf16* lnbC = (bf16*)(r0 + 33554432);        // 16777216 B
  bf16* xnbQ = (bf16*)(r0 + 50331648);        // 33554432 B
  bf16* xnbC = (bf16*)(r0 + 83886080);        // 16777216 B
  bf16* hQ   = (bf16*)r0;                     // 67108864 B (NQ x 256)
  bf16* hC   = (bf16*)(r0 + 67108864);        // 33554432 B (NC x 256)
  bf16* projQ = (bf16*)alloc((size_t)NQn * 128 * 2);
  bf16* projC = (bf16*)alloc((size_t)NCn * 128 * 2);
  char* msgR  = alloc((size_t)(NQn + NCn) * 128 * 2);
  bf16* msgQ  = (bf16*)msgR;                  // 33554432 B
  bf16* msgC  = (bf16*)(msgR + (size_t)NQn * 128 * 2);
  // ebuf overlays msgQ (dead until gather; bucketB finishes first)
  uint2* ebufQC = (uint2*)msgR;               // 8 MB
  uint2* ebufCQ = (uint2*)(msgR + 8388608);   // 8 MB
  bf16* WresQt = (bf16*)alloc(128 * 128 * 2);
  bf16* WresCt = (bf16*)alloc(128 * 128 * 2);
  bf16* WrelQCt = (bf16*)alloc(128 * 128 * 2);
  bf16* WrelCQt = (bf16*)alloc(128 * 128 * 2);
  bf16* W1Qt = (bf16*)alloc(256 * 256 * 2);
  bf16* W1Ct = (bf16*)alloc(256 * 256 * 2);
  bf16* W2Qt = (bf16*)alloc(128 * 256 * 2);
  bf16* W2Ct = (bf16*)alloc(128 * 256 * 2);
  int* offsQC = (int*)alloc((size_t)(NCn + 1) * 4);
  int* offsCQ = (int*)alloc((size_t)(NQn + 1) * 4);
  int* csrQC  = (int*)alloc((size_t)En * 4);
  int* csrCQ  = (int*)alloc((size_t)En * 4);
  int* bsumQC = (int*)alloc(1024);
  int* bsumCQ = (int*)alloc(1024);
  int* gcurQC = (int*)alloc(256 * 4);
  int* gcurCQ = (int*)alloc(512 * 4);

  float* outQ = (float*)d_out;
  float* outC = (float*)d_out + (size_t)NQn * 128;

  // 1. weight transpose+cast
  wtrans_all<<<dim3(256, 8), 256, 0, stream>>>(
      Wres_Q, WresQt, Wres_C, WresCt, Wrel_QC, WrelQCt, Wrel_CQ, WrelCQt,
      W1_Q, W1Qt, W1_C, W1Ct, W2_Q, W2Qt, W2_C, W2Ct);

  // 2. LayerNorm -> bf16
  ln_kernel<<<NQn / 4, 256, 0, stream>>>(H_Q, ln_g_Q, ln_b_Q, lnbQ, NQn);
  ln_kernel<<<NCn / 4, 256, 0, stream>>>(H_C, ln_g_C, ln_b_C, lnbC, NCn);

  // 3. proj = LN(H) @ Wres  (bf16 out)
  gemm_kernel<ASRC_BF16, EPI_BF16, 1><<<dim3(NQn / 128, 1), 256, 0, stream>>>(
      lnbQ, nullptr, WresQt, nullptr, nullptr, nullptr, projQ, nullptr, 128, 0, 128);
  gemm_kernel<ASRC_BF16, EPI_BF16, 1><<<dim3(NCn / 128, 1), 256, 0, stream>>>(
      lnbC, nullptr, WresCt, nullptr, nullptr, nullptr, projC, nullptr, 128, 0, 128);

  // 4. Xn = (H @ Wrel) * invsqrt(deg_src)  (bf16 out)
  gemm_kernel<ASRC_F32, EPI_RSCL, 1><<<dim3(NQn / 128, 1), 256, 0, stream>>>(
      H_Q, nullptr, WrelQCt, nullptr, deg_QC_src, nullptr, xnbQ, nullptr, 128, 0, 128);
  gemm_kernel<ASRC_F32, EPI_RSCL, 1><<<dim3(NCn / 128, 1), 256, 0, stream>>>(
      H_C, nullptr, WrelCQt, nullptr, deg_CQ_src, nullptr, xnbC, nullptr, 128, 0, 128);

  // 5. CSR build: deg-scan -> offs; bucketed partition -> ebuf; bucket fill -> csr
  scan_local2<<<NCn / 1024 + NQn / 1024, 1024, 0, stream>>>(
      deg_QC_dst, offsQC, bsumQC, NCn / 1024, deg_CQ_dst, offsCQ, bsumCQ);
  scan_bsum2<<<2, 64, 0, stream>>>(bsumQC, NCn / 1024, bsumCQ, NQn / 1024);
  scan_add2<<<NQn / 256, 256, 0, stream>>>(offsQC, bsumQC, gcurQC,
                                           offsCQ, bsumCQ, gcurCQ);
  bucketA<256><<<En / CHUNK, 256, 0, stream>>>(eQC_src, eQC_dst, gcurQC, ebufQC);
  bucketA<512><<<En / CHUNK, 256, 0, stream>>>(eCQ_src, eCQ_dst, gcurCQ, ebufCQ);
  bucketB<<<NCn / 256, 256, 0, stream>>>(ebufQC, offsQC, csrQC);
  bucketB<<<NQn / 256, 256, 0, stream>>>(ebufCQ, offsCQ, csrCQ);

  // 6. gather (scatter-free SpMM): msgC from xnbQ, msgQ from xnbC
  gather_kernel<<<NCn / 4, 256, 0, stream>>>(xnbQ, csrQC, offsQC, deg_QC_dst,
                                             gate_QC, msgC, NCn);
  gather_kernel<<<NQn / 4, 256, 0, stream>>>(xnbC, csrCQ, offsCQ, deg_CQ_dst,
                                             gate_CQ, msgQ, NQn);

  // 7. MLP layer 1: h = gelu([proj | msg] @ W1 + b1)   (writes over R0 — LN/Xn dead)
  gemm_kernel<ASRC_BF16, EPI_GELU, 2><<<dim3(NQn / 128, 2), 256, 0, stream>>>(
      projQ, msgQ, W1Qt, b1_Q, nullptr, nullptr, hQ, nullptr, 128, 0, 256);
  gemm_kernel<ASRC_BF16, EPI_GELU, 2><<<dim3(NCn / 128, 2), 256, 0, stream>>>(
      projC, msgC, W1Ct, b1_C, nullptr, nullptr, hC, nullptr, 128, 0, 256);

  // 8. MLP layer 2 + residual: out = proj + h @ W2 + b2  (f32 out)
  gemm_kernel<ASRC_BF16, EPI_RES, 2><<<dim3(NQn / 128, 1), 256, 0, stream>>>(
      hQ, hQ, W2Qt, b2_Q, nullptr, projQ, nullptr, outQ, 256, 128, 128);
  gemm_kernel<ASRC_BF16, EPI_RES, 2><<<dim3(NCn / 128, 1), 256, 0, stream>>>(
      hC, hC, W2Ct, b2_C, nullptr, projC, nullptr, outC, 256, 128, 128);
}